// Round 6
// baseline (89.657 us; speedup 1.0000x reference)
//
#include <hip/hip_runtime.h>

// SoftSmoothAP on MI355X. B=384, C=48, D=512. Output: scalar f32 loss = 1 - AP.
//
//   simk[i,q] = <preds_i, preds_q> * 100*log2(e)        (pre-scaled)
//   sg(i,p,q) = 1/(1+exp2(simk[i,p] - simk[i,q]))       (clamp dropped: saturates
//               to 0/1 within 2e-22 of the reference's +-50 clip)
//   denomf[i,p] = 0.5 + sum_{all q} sg                   (== 1 + sum_{q!=p} sg)
//   loss = 1 - (1/B) sum_{i,c} sl[i,c]*w[c] *
//            sum_{p in P_c} (0.5 + sum_{q in P_c} sg) / denomf[i,p]
//
// Latency-hiding structure: denom kernel is LDS-free, 4 threads per (i,p)
// (96 q each) -> 590K threads (32 waves/CU) x 4 independent accumulator
// chains; phaseB is 256-thr blocks x (i, entry-quarter) with 4-way unrolled
// gather loop.

#define BB 384
#define CC 48
#define DD 512
#define MAXE 3072
#define SCALE 144.269504089f  // 100 * log2(e)

__device__ __forceinline__ float sigm_pre(float x) {
    return __builtin_amdgcn_rcpf(1.0f + __builtin_amdgcn_exp2f(x));
}

// ---- 1. sim rows (blocks 0..191, 2 rows each) + prep (block 192) -------------
__global__ __launch_bounds__(384) void simprep_kernel(
    const float* __restrict__ preds, const float* __restrict__ softlabels,
    float* __restrict__ simk, float* __restrict__ wclass,
    int* __restrict__ cls_idx, int* __restrict__ cls_off,
    int* __restrict__ flat_pack, int* __restrict__ nE, float* __restrict__ out) {
    int tid = threadIdx.x;
    int wave = tid >> 6, lane = tid & 63;

    if (blockIdx.x < BB / 2) {
        // ---- sim: 2 rows per block, pre-scaled ----
        int i0 = blockIdx.x * 2;
        __shared__ __align__(16) float4 rows[2][DD / 4];
        const float4* src = reinterpret_cast<const float4*>(preds + i0 * DD);
        for (int v = tid; v < 2 * DD / 4; v += 384) (&rows[0][0])[v] = src[v];
        __syncthreads();
        int q = tid;
        const float4* pq = reinterpret_cast<const float4*>(preds + q * DD);
        float a0 = 0.f, a1 = 0.f;
#pragma unroll 8
        for (int d4 = 0; d4 < DD / 4; ++d4) {
            float4 b = pq[d4];
            float4 r0 = rows[0][d4];
            float4 r1 = rows[1][d4];
            a0 += r0.x * b.x + r0.y * b.y + r0.z * b.z + r0.w * b.w;
            a1 += r1.x * b.x + r1.y * b.y + r1.z * b.z + r1.w * b.w;
        }
        simk[i0 * BB + q] = a0 * SCALE;
        simk[(i0 + 1) * BB + q] = a1 * SCALE;
    } else {
        // ---- prep: class lists, weights, flat (c,p) list, out init ----
        __shared__ int s_cnt[CC];
        __shared__ int s_soff[CC + 1];
        for (int c = wave; c < CC; c += 6) {
            int base = 0;
#pragma unroll
            for (int t = 0; t < BB / 64; ++t) {
                int p = t * 64 + lane;
                bool pos = softlabels[p * CC + c] > 0.0f;
                unsigned long long m = __ballot(pos);
                if (pos)
                    cls_idx[c * BB + base + __popcll(m & ((1ull << lane) - 1ull))] = p;
                base += __popcll(m);
            }
            if (lane == 0) {
                s_cnt[c] = base;
                wclass[c] = (base >= 4) ? (1.0f / (float)base) : 0.0f;
            }
        }
        __syncthreads();
        if (tid < 64) {
            int v = (tid < CC) ? s_cnt[tid] : 0;
#pragma unroll
            for (int d = 1; d < 64; d <<= 1) {
                int o = __shfl_up(v, d, 64);
                if (tid >= d) v += o;
            }
            if (tid < CC) s_soff[tid + 1] = v;
            if (tid == 0) s_soff[0] = 0;
            if (tid == CC - 1) *nE = v;
        }
        __syncthreads();
        if (tid <= CC) cls_off[tid] = s_soff[tid];
        for (int c = wave; c < CC; c += 6) {
            int off = s_soff[c], cnt = s_cnt[c];
            for (int k = lane; k < cnt; k += 64)
                flat_pack[off + k] = (c << 16) | cls_idx[c * BB + k];
        }
        if (tid == 0) out[0] = 1.0f;
    }
}

// ---- 2. denom: 4 threads per (i,p), 96 q each; no LDS, 4 acc chains ----------
#define QC 96
__global__ __launch_bounds__(256) void denom_kernel(const float* __restrict__ simk,
                                                    float* __restrict__ denomf) {
    int gid = blockIdx.x * 256 + threadIdx.x;  // 384*384*4 total
    int qc = gid & 3;
    int ip = gid >> 2;
    int i = ip / BB;
    int p = ip - i * BB;
    const float* row = simk + i * BB;
    float sp = row[p];
    const float4* q4 = reinterpret_cast<const float4*>(row + qc * QC);
    float a0 = 0.f, a1 = 0.f, a2 = 0.f, a3 = 0.f;
#pragma unroll 6
    for (int t = 0; t < QC / 4; ++t) {
        float4 v = q4[t];
        a0 += sigm_pre(sp - v.x);
        a1 += sigm_pre(sp - v.y);
        a2 += sigm_pre(sp - v.z);
        a3 += sigm_pre(sp - v.w);
    }
    float s = (a0 + a1) + (a2 + a3);
    s += __shfl_xor(s, 1, 64);
    s += __shfl_xor(s, 2, 64);
    if (qc == 0) denomf[ip] = 0.5f + s;  // full denominator (diag 0.5 inside sum)
}

// ---- 3. phaseB: block = (i, entry-quarter), 256 threads ----------------------
__global__ __launch_bounds__(256) void phaseB_kernel(
    const float* __restrict__ simk, const float* __restrict__ denomf,
    const float* __restrict__ softlabels, const float* __restrict__ wclass,
    const int* __restrict__ cls_off, const int* __restrict__ flat_pack,
    const int* __restrict__ nE_p, float* __restrict__ out) {
    int i = blockIdx.x >> 2, quarter = blockIdx.x & 3;
    int tid = threadIdx.x;
    int wave = tid >> 6, lane = tid & 63;

    __shared__ float s_simk[BB];
    __shared__ float s_wsl[CC];
    __shared__ int s_offs[CC + 1];
    __shared__ unsigned short s_pl[MAXE];
    __shared__ float s_red[4];

    int nE = *nE_p;
    for (int t = tid; t < BB; t += 256) s_simk[t] = simk[i * BB + t];
    if (tid < CC) s_wsl[tid] = wclass[tid] * softlabels[i * CC + tid];
    if (tid <= CC) s_offs[tid] = cls_off[tid];
    for (int e = tid; e < nE; e += 256)
        s_pl[e] = (unsigned short)(flat_pack[e] & 0xFFFF);
    __syncthreads();

    int e0 = (nE * quarter) >> 2, e1 = (nE * (quarter + 1)) >> 2;
    float part = 0.f;
    for (int e = e0 + tid; e < e1; e += 256) {
        int pk = flat_pack[e];
        int c = pk >> 16, p = pk & 0xFFFF;
        int off = s_offs[c], m = s_offs[c + 1] - off;
        float spk = s_simk[p];
        float b0 = 0.f, b1 = 0.f, b2 = 0.f, b3 = 0.f;
        int k = 0;
        for (; k + 3 < m; k += 4) {
            float v0 = s_simk[s_pl[off + k]];
            float v1 = s_simk[s_pl[off + k + 1]];
            float v2 = s_simk[s_pl[off + k + 2]];
            float v3 = s_simk[s_pl[off + k + 3]];
            b0 += sigm_pre(spk - v0);
            b1 += sigm_pre(spk - v1);
            b2 += sigm_pre(spk - v2);
            b3 += sigm_pre(spk - v3);
        }
        for (; k < m; ++k) b0 += sigm_pre(spk - s_simk[s_pl[off + k]]);
        float s = (b0 + b1) + (b2 + b3);
        // s includes q==p (=0.5): numerator = 0.5 + s
        part += (0.5f + s) * __builtin_amdgcn_rcpf(denomf[i * BB + p]) * s_wsl[c];
    }

    for (int off = 32; off > 0; off >>= 1) part += __shfl_down(part, off, 64);
    if (lane == 0) s_red[wave] = part;
    __syncthreads();
    if (tid == 0) {
        float tot = (s_red[0] + s_red[1]) + (s_red[2] + s_red[3]);
        atomicAdd(out, -tot * (1.0f / (float)BB));
    }
}

extern "C" void kernel_launch(void* const* d_in, const int* in_sizes, int n_in,
                              void* d_out, int out_size, void* d_ws, size_t ws_size,
                              hipStream_t stream) {
    const float* preds = (const float*)d_in[0];       // (384,512) f32
    const float* softlabels = (const float*)d_in[1];  // (384,48) f32
    float* out = (float*)d_out;

    char* ws = (char*)d_ws;
    float* simk     = (float*)(ws + 0);         // 589824
    float* denomf   = (float*)(ws + 589824);    // 589824
    float* wclass   = (float*)(ws + 1179648);   // 192
    int*   cls_off  = (int*)(ws + 1179840);     // 256 (49 used)
    int*   cls_idx  = (int*)(ws + 1180096);     // 73728
    int*   flat_pk  = (int*)(ws + 1253824);     // 12288
    int*   nE       = (int*)(ws + 1266112);     // 4

    simprep_kernel<<<BB / 2 + 1, 384, 0, stream>>>(preds, softlabels, simk, wclass,
                                                   cls_idx, cls_off, flat_pk, nE, out);
    denom_kernel<<<(BB * BB * 4) / 256, 256, 0, stream>>>(simk, denomf);
    phaseB_kernel<<<BB * 4, 256, 0, stream>>>(simk, denomf, softlabels, wclass,
                                              cls_off, flat_pk, nE, out);
}

// Round 7
// 65.188 us; speedup vs baseline: 1.3754x; 1.3754x over previous
//
#include <hip/hip_runtime.h>

// SoftSmoothAP on MI355X. B=384, C=48, D=512. Output: scalar f32 loss = 1 - AP.
//
//   simk[i,q] = <preds_i, preds_q> * 100*log2(e)        (pre-scaled)
//   sg(i,p,q) = 1/(1+exp2(simk[i,p] - simk[i,q]))       (clamp dropped: saturates
//               to 0/1 within 2e-22 of the reference's +-50 clip)
//   denom[i,p] = 0.5 + sum_{all q} sg                    (== 1 + sum_{q!=p} sg)
//   loss = 1 - (1/B) sum_{i,c} sl[i,c]*w[c] *
//            sum_{p in P_c} (0.5 + sum_{q in P_c} sg) / denom[i,p]
//
// Structure (round-5 shape + ILP fixes):
//   kernel 1: sim (4 rows/block, 96 blocks) + prep (block 96)
//   kernel 2: mega768, block=(i, p-half): LDS-staged row, denom with 4 acc
//             chains, fused phaseB with 4-way unrolled gathers, partial-sum
//             store + last-block final reduction (no same-address atomic burst).

#define BB 384
#define CC 48
#define DD 512
#define HALF 192
#define MAXE 3072
#define GRID2 (BB * 2)
#define SCALE 144.269504089f  // 100 * log2(e)

__device__ __forceinline__ float sigm_pre(float x) {
    return __builtin_amdgcn_rcpf(1.0f + __builtin_amdgcn_exp2f(x));
}

// ---- 1. sim rows (blocks 0..95, 4 rows each) + prep (block 96) ---------------
__global__ __launch_bounds__(384) void simprep_kernel(
    const float* __restrict__ preds, const float* __restrict__ softlabels,
    float* __restrict__ simk, float* __restrict__ wclass,
    int* __restrict__ cls_idx, int* __restrict__ cls_off,
    int* __restrict__ ent_lo, int* __restrict__ ent_hi,
    int* __restrict__ flat_pack, int* __restrict__ nE3,
    int* __restrict__ done_cnt) {
    int tid = threadIdx.x;
    int wave = tid >> 6, lane = tid & 63;

    if (blockIdx.x < BB / 4) {
        // ---- sim: 4 rows per block, pre-scaled ----
        int i0 = blockIdx.x * 4;
        __shared__ __align__(16) float4 rows[4][DD / 4];
        const float4* src = reinterpret_cast<const float4*>(preds + i0 * DD);
        for (int v = tid; v < 4 * DD / 4; v += 384) (&rows[0][0])[v] = src[v];
        __syncthreads();
        int q = tid;
        const float4* pq = reinterpret_cast<const float4*>(preds + q * DD);
        float a0 = 0.f, a1 = 0.f, a2 = 0.f, a3 = 0.f;
#pragma unroll 4
        for (int d4 = 0; d4 < DD / 4; ++d4) {
            float4 b = pq[d4];
            float4 r0 = rows[0][d4];
            float4 r1 = rows[1][d4];
            float4 r2 = rows[2][d4];
            float4 r3 = rows[3][d4];
            a0 += r0.x * b.x + r0.y * b.y + r0.z * b.z + r0.w * b.w;
            a1 += r1.x * b.x + r1.y * b.y + r1.z * b.z + r1.w * b.w;
            a2 += r2.x * b.x + r2.y * b.y + r2.z * b.z + r2.w * b.w;
            a3 += r3.x * b.x + r3.y * b.y + r3.z * b.z + r3.w * b.w;
        }
        simk[(i0 + 0) * BB + q] = a0 * SCALE;
        simk[(i0 + 1) * BB + q] = a1 * SCALE;
        simk[(i0 + 2) * BB + q] = a2 * SCALE;
        simk[(i0 + 3) * BB + q] = a3 * SCALE;
    } else {
        // ---- prep: class lists, weights, flat + half-partitioned entry lists
        __shared__ int s_cnt[CC];
        __shared__ int s_lcnt[CC];
        __shared__ int s_soff[CC + 1];
        __shared__ int s_loff[CC + 1];
        __shared__ int s_hoff[CC + 1];
        for (int c = wave; c < CC; c += 6) {
            int base = 0, lbase = 0;
#pragma unroll
            for (int t = 0; t < BB / 64; ++t) {
                int p = t * 64 + lane;
                bool pos = softlabels[p * CC + c] > 0.0f;
                unsigned long long m = __ballot(pos);
                if (pos)
                    cls_idx[c * BB + base + __popcll(m & ((1ull << lane) - 1ull))] = p;
                base += __popcll(m);
                if (t < 3) lbase += __popcll(m);  // p<192 <=> t<3
            }
            if (lane == 0) {
                s_cnt[c] = base;
                s_lcnt[c] = lbase;
                wclass[c] = (base >= 4) ? (1.0f / (float)base) : 0.0f;
            }
        }
        __syncthreads();
        if (tid < 64) {
            int a = (tid < CC) ? s_cnt[tid] : 0;
            int l = (tid < CC) ? s_lcnt[tid] : 0;
            int hg = a - l;
#pragma unroll
            for (int d = 1; d < 64; d <<= 1) {
                int oa = __shfl_up(a, d, 64);
                int ol = __shfl_up(l, d, 64);
                int oh = __shfl_up(hg, d, 64);
                if (tid >= d) { a += oa; l += ol; hg += oh; }
            }
            if (tid < CC) { s_soff[tid + 1] = a; s_loff[tid + 1] = l; s_hoff[tid + 1] = hg; }
            if (tid == 0) { s_soff[0] = 0; s_loff[0] = 0; s_hoff[0] = 0; }
            if (tid == CC - 1) { nE3[0] = a; nE3[1] = l; nE3[2] = hg; }
        }
        __syncthreads();
        if (tid <= CC) cls_off[tid] = s_soff[tid];
        for (int c = wave; c < CC; c += 6) {
            int off = s_soff[c], cnt = s_cnt[c], L = s_lcnt[c];
            int lo = s_loff[c], ho = s_hoff[c];
            for (int k = lane; k < cnt; k += 64) {
                int p = cls_idx[c * BB + k];
                int pk = (c << 16) | p;
                flat_pack[off + k] = pk;
                if (k < L) ent_lo[lo + k] = pk;
                else       ent_hi[ho + (k - L)] = pk;
            }
        }
        if (tid == 0) *done_cnt = 0;
    }
}

// ---- 2. mega768: denom (own p-half) + phaseB, block = (i, h) -----------------
__global__ __launch_bounds__(384) void mega_kernel(
    const float* __restrict__ simk, const float* __restrict__ softlabels,
    const float* __restrict__ wclass, const int* __restrict__ cls_off,
    const int* __restrict__ flat_pack, const int* __restrict__ ent_lo,
    const int* __restrict__ ent_hi, const int* __restrict__ nE3,
    float* __restrict__ partials, int* __restrict__ done_cnt,
    float* __restrict__ out) {
    int i = blockIdx.x >> 1, h = blockIdx.x & 1;
    int tid = threadIdx.x;
    int wave = tid >> 6, lane = tid & 63;

    __shared__ __align__(16) float s_simk[BB];
    __shared__ float s_part[384];
    __shared__ float s_inv[HALF];
    __shared__ float s_wsl[CC];
    __shared__ int s_offs[CC + 1];
    __shared__ unsigned short s_pl[MAXE];
    __shared__ float s_red[6];
    __shared__ int s_last;

    int nE = nE3[0];
    s_simk[tid] = simk[i * BB + tid];
    if (tid < CC) s_wsl[tid] = wclass[tid] * softlabels[i * CC + tid];
    if (tid <= CC) s_offs[tid] = cls_off[tid];
    for (int e = tid; e < nE; e += 384) s_pl[e] = (unsigned short)(flat_pack[e] & 0xFFFF);
    __syncthreads();

    // --- denominators for this half: 2 threads/p over q-halves, 4 acc chains
    {
        int pl = tid % HALF;
        int chunk = tid / HALF;
        float spk = s_simk[h * HALF + pl];
        const float4* sv = reinterpret_cast<const float4*>(s_simk + chunk * HALF);
        float a0 = 0.f, a1 = 0.f, a2 = 0.f, a3 = 0.f;
#pragma unroll 4
        for (int q4 = 0; q4 < HALF / 4; ++q4) {
            float4 v = sv[q4];  // same-address broadcast: conflict-free
            a0 += sigm_pre(spk - v.x);
            a1 += sigm_pre(spk - v.y);
            a2 += sigm_pre(spk - v.z);
            a3 += sigm_pre(spk - v.w);
        }
        s_part[tid] = (a0 + a1) + (a2 + a3);
    }
    __syncthreads();
    if (tid < HALF) {
        float d = 0.5f + s_part[tid] + s_part[tid + HALF];
        s_inv[tid] = __builtin_amdgcn_rcpf(d);
    }
    __syncthreads();

    // --- positive-rank phase over this half's entries, 4-way unrolled gathers
    const int* ent = h ? ent_hi : ent_lo;
    int n = nE3[1 + h];
    float part = 0.f;
    for (int e = tid; e < n; e += 384) {
        int pk = ent[e];
        int c = pk >> 16, p = pk & 0xFFFF;
        int off = s_offs[c], m = s_offs[c + 1] - off;
        float spk = s_simk[p];
        float b0 = 0.f, b1 = 0.f, b2 = 0.f, b3 = 0.f;
        int k = 0;
        for (; k + 3 < m; k += 4) {
            float v0 = s_simk[s_pl[off + k]];
            float v1 = s_simk[s_pl[off + k + 1]];
            float v2 = s_simk[s_pl[off + k + 2]];
            float v3 = s_simk[s_pl[off + k + 3]];
            b0 += sigm_pre(spk - v0);
            b1 += sigm_pre(spk - v1);
            b2 += sigm_pre(spk - v2);
            b3 += sigm_pre(spk - v3);
        }
        for (; k < m; ++k) b0 += sigm_pre(spk - s_simk[s_pl[off + k]]);
        float s = (b0 + b1) + (b2 + b3);
        // s includes q==p (=0.5): numerator = 0.5 + s
        part += (0.5f + s) * s_inv[p - h * HALF] * s_wsl[c];
    }

    for (int off = 32; off > 0; off >>= 1) part += __shfl_down(part, off, 64);
    if (lane == 0) s_red[wave] = part;
    __syncthreads();
    if (tid == 0) {
        float tot = 0.f;
#pragma unroll
        for (int w = 0; w < 6; ++w) tot += s_red[w];
        partials[blockIdx.x] = tot;
        __threadfence();
        int old = atomicAdd(done_cnt, 1);
        s_last = (old == GRID2 - 1) ? 1 : 0;
    }
    __syncthreads();
    if (s_last) {
        // final deterministic reduction of 768 partials by this block
        float v = 0.f;
        for (int t = tid; t < GRID2; t += 384)
            v += __hip_atomic_load(&partials[t], __ATOMIC_RELAXED,
                                   __HIP_MEMORY_SCOPE_AGENT);
        for (int off = 32; off > 0; off >>= 1) v += __shfl_down(v, off, 64);
        if (lane == 0) s_red[wave] = v;
        __syncthreads();
        if (tid == 0) {
            float tot = 0.f;
#pragma unroll
            for (int w = 0; w < 6; ++w) tot += s_red[w];
            out[0] = 1.0f - tot * (1.0f / (float)BB);
        }
    }
}

extern "C" void kernel_launch(void* const* d_in, const int* in_sizes, int n_in,
                              void* d_out, int out_size, void* d_ws, size_t ws_size,
                              hipStream_t stream) {
    const float* preds = (const float*)d_in[0];       // (384,512) f32
    const float* softlabels = (const float*)d_in[1];  // (384,48) f32
    float* out = (float*)d_out;

    char* ws = (char*)d_ws;
    float* simk     = (float*)(ws + 0);         // 589824
    float* wclass   = (float*)(ws + 589824);    // 192
    int*   cls_off  = (int*)(ws + 590016);      // 256 (49 used)
    int*   cls_idx  = (int*)(ws + 590272);      // 73728
    int*   flat_pk  = (int*)(ws + 664000);      // 12288
    int*   ent_lo   = (int*)(ws + 676288);      // 12288
    int*   ent_hi   = (int*)(ws + 688576);      // 12288
    int*   nE3      = (int*)(ws + 700864);      // 16
    int*   done_cnt = (int*)(ws + 700880);      // 4
    float* partials = (float*)(ws + 700928);    // 768*4 = 3072

    simprep_kernel<<<BB / 4 + 1, 384, 0, stream>>>(preds, softlabels, simk, wclass,
                                                   cls_idx, cls_off, ent_lo, ent_hi,
                                                   flat_pk, nE3, done_cnt);
    mega_kernel<<<GRID2, 384, 0, stream>>>(simk, softlabels, wclass, cls_off,
                                           flat_pk, ent_lo, ent_hi, nE3,
                                           partials, done_cnt, out);
}

// Round 8
// 59.477 us; speedup vs baseline: 1.5074x; 1.0960x over previous
//
#include <hip/hip_runtime.h>

// SoftSmoothAP on MI355X. B=384, C=48, D=512. Output: scalar f32 loss = 1 - AP.
//
//   simk[i,q] = <preds_i, preds_q> * 100*log2(e)        (pre-scaled)
//   sg(i,p,q) = 1/(1+exp2(simk[i,p] - simk[i,q]))       (clamp dropped: saturates
//               to 0/1 within 2e-22 of the reference's +-50 clip)
//   denom[i,p] = 0.5 + sum_{all q} sg                    (== 1 + sum_{q!=p} sg)
//   loss = 1 - (1/B) sum_{i,c} sl[i,c]*w[c] *
//            sum_{p in P_c} (0.5 + sum_{q in P_c} sg) / denom[i,p]
//
// Structure = round-5 skeleton (best: 58.8us) + ILP-only upgrades:
//   kernel 1: sim (2 rows/block, 192 blocks) + prep (block 192)
//   kernel 2: mega768, block=(i, p-half): LDS row, denom with 8 indep acc
//             chains, fused phaseB with 4-way unrolled gathers, single
//             atomicAdd per block (no fences, no done-counters).

#define BB 384
#define CC 48
#define DD 512
#define HALF 192
#define MAXE 3072
#define SCALE 144.269504089f  // 100 * log2(e)

__device__ __forceinline__ float sigm_pre(float x) {
    return __builtin_amdgcn_rcpf(1.0f + __builtin_amdgcn_exp2f(x));
}

// ---- 1. sim rows (blocks 0..191, 2 rows each) + prep (block 192) -------------
__global__ __launch_bounds__(384) void simprep_kernel(
    const float* __restrict__ preds, const float* __restrict__ softlabels,
    float* __restrict__ simk, float* __restrict__ wclass,
    int* __restrict__ cls_idx, int* __restrict__ cls_off,
    int* __restrict__ flat_pack, int* __restrict__ ent_lo, int* __restrict__ ent_hi,
    int* __restrict__ nE3, float* __restrict__ out) {
    int tid = threadIdx.x;
    int wave = tid >> 6, lane = tid & 63;

    if (blockIdx.x < BB / 2) {
        // ---- sim: 2 rows per block, pre-scaled ----
        int i0 = blockIdx.x * 2;
        __shared__ __align__(16) float4 rows[2][DD / 4];
        const float4* src = reinterpret_cast<const float4*>(preds + i0 * DD);
        for (int v = tid; v < 2 * DD / 4; v += 384) (&rows[0][0])[v] = src[v];
        __syncthreads();
        int q = tid;
        const float4* pq = reinterpret_cast<const float4*>(preds + q * DD);
        float a0 = 0.f, a1 = 0.f;
#pragma unroll 8
        for (int d4 = 0; d4 < DD / 4; ++d4) {
            float4 b = pq[d4];
            float4 r0 = rows[0][d4];
            float4 r1 = rows[1][d4];
            a0 += r0.x * b.x + r0.y * b.y + r0.z * b.z + r0.w * b.w;
            a1 += r1.x * b.x + r1.y * b.y + r1.z * b.z + r1.w * b.w;
        }
        simk[i0 * BB + q] = a0 * SCALE;
        simk[(i0 + 1) * BB + q] = a1 * SCALE;
    } else {
        // ---- prep: class lists, weights, flat + half-partitioned entry lists
        __shared__ int s_cnt[CC];    // class count
        __shared__ int s_lcnt[CC];   // count with p < 192
        __shared__ int s_soff[CC + 1];
        __shared__ int s_loff[CC + 1];
        __shared__ int s_hoff[CC + 1];
        for (int c = wave; c < CC; c += 6) {
            int base = 0, lbase = 0;
#pragma unroll
            for (int t = 0; t < BB / 64; ++t) {
                int p = t * 64 + lane;
                bool pos = softlabels[p * CC + c] > 0.0f;
                unsigned long long m = __ballot(pos);
                if (pos)
                    cls_idx[c * BB + base + __popcll(m & ((1ull << lane) - 1ull))] = p;
                base += __popcll(m);
                if (t < 3) lbase += __popcll(m);  // p<192 <=> t<3
            }
            if (lane == 0) {
                s_cnt[c] = base;
                s_lcnt[c] = lbase;
                wclass[c] = (base >= 4) ? (1.0f / (float)base) : 0.0f;
            }
        }
        __syncthreads();
        if (tid < 64) {
            int a = (tid < CC) ? s_cnt[tid] : 0;
            int l = (tid < CC) ? s_lcnt[tid] : 0;
            int hg = a - l;
#pragma unroll
            for (int d = 1; d < 64; d <<= 1) {
                int oa = __shfl_up(a, d, 64);
                int ol = __shfl_up(l, d, 64);
                int oh = __shfl_up(hg, d, 64);
                if (tid >= d) { a += oa; l += ol; hg += oh; }
            }
            if (tid < CC) { s_soff[tid + 1] = a; s_loff[tid + 1] = l; s_hoff[tid + 1] = hg; }
            if (tid == 0) { s_soff[0] = 0; s_loff[0] = 0; s_hoff[0] = 0; }
            if (tid == CC - 1) { nE3[0] = a; nE3[1] = l; nE3[2] = hg; }
        }
        __syncthreads();
        if (tid <= CC) cls_off[tid] = s_soff[tid];
        for (int c = wave; c < CC; c += 6) {
            int off = s_soff[c], cnt = s_cnt[c], L = s_lcnt[c];
            int lo = s_loff[c], ho = s_hoff[c];
            for (int k = lane; k < cnt; k += 64) {
                int p = cls_idx[c * BB + k];  // ascending p within class
                int pk = (c << 16) | p;
                flat_pack[off + k] = pk;
                if (k < L) ent_lo[lo + k] = pk;
                else       ent_hi[ho + (k - L)] = pk;
            }
        }
        if (tid == 0) out[0] = 1.0f;
    }
}

// ---- 2. mega768: denom (own p-half, 8 acc chains) + phaseB, block = (i, h) ---
__global__ __launch_bounds__(384) void mega_kernel(
    const float* __restrict__ simk, const float* __restrict__ softlabels,
    const float* __restrict__ wclass, const int* __restrict__ cls_off,
    const int* __restrict__ flat_pack, const int* __restrict__ ent_lo,
    const int* __restrict__ ent_hi, const int* __restrict__ nE3,
    float* __restrict__ out) {
    int i = blockIdx.x >> 1, h = blockIdx.x & 1;
    int tid = threadIdx.x;
    int wave = tid >> 6, lane = tid & 63;

    __shared__ __align__(16) float s_simk[BB];
    __shared__ float s_part[384];
    __shared__ float s_inv[HALF];
    __shared__ float s_wsl[CC];
    __shared__ int s_offs[CC + 1];
    __shared__ unsigned short s_pl[MAXE];
    __shared__ float s_red[6];

    int nE = nE3[0];
    s_simk[tid] = simk[i * BB + tid];
    if (tid < CC) s_wsl[tid] = wclass[tid] * softlabels[i * CC + tid];
    if (tid <= CC) s_offs[tid] = cls_off[tid];
    for (int e = tid; e < nE; e += 384) s_pl[e] = (unsigned short)(flat_pack[e] & 0xFFFF);
    __syncthreads();

    // --- denominators for this half: 2 threads/p over q-halves, 8 acc chains
    {
        int pl = tid % HALF;     // lane-contiguous p
        int chunk = tid / HALF;  // wave-uniform q-half
        float spk = s_simk[h * HALF + pl];
        const float4* sv = reinterpret_cast<const float4*>(s_simk + chunk * HALF);
        float a0 = 0.f, a1 = 0.f, a2 = 0.f, a3 = 0.f;
        float a4 = 0.f, a5 = 0.f, a6 = 0.f, a7 = 0.f;
#pragma unroll 4
        for (int t = 0; t < HALF / 8; ++t) {
            float4 v0 = sv[2 * t];      // same-address broadcast: conflict-free
            float4 v1 = sv[2 * t + 1];
            a0 += sigm_pre(spk - v0.x);
            a1 += sigm_pre(spk - v0.y);
            a2 += sigm_pre(spk - v0.z);
            a3 += sigm_pre(spk - v0.w);
            a4 += sigm_pre(spk - v1.x);
            a5 += sigm_pre(spk - v1.y);
            a6 += sigm_pre(spk - v1.z);
            a7 += sigm_pre(spk - v1.w);
        }
        s_part[tid] = ((a0 + a1) + (a2 + a3)) + ((a4 + a5) + (a6 + a7));
    }
    __syncthreads();
    if (tid < HALF) {
        float d = 0.5f + s_part[tid] + s_part[tid + HALF];
        s_inv[tid] = __builtin_amdgcn_rcpf(d);
    }
    __syncthreads();

    // --- positive-rank phase over this half's entries, 4-way unrolled gathers
    const int* ent = h ? ent_hi : ent_lo;
    int n = nE3[1 + h];
    float part = 0.f;
    for (int e = tid; e < n; e += 384) {
        int pk = ent[e];
        int c = pk >> 16, p = pk & 0xFFFF;
        int off = s_offs[c], m = s_offs[c + 1] - off;
        float spk = s_simk[p];
        float b0 = 0.f, b1 = 0.f, b2 = 0.f, b3 = 0.f;
        int k = 0;
        for (; k + 3 < m; k += 4) {
            float v0 = s_simk[s_pl[off + k]];
            float v1 = s_simk[s_pl[off + k + 1]];
            float v2 = s_simk[s_pl[off + k + 2]];
            float v3 = s_simk[s_pl[off + k + 3]];
            b0 += sigm_pre(spk - v0);
            b1 += sigm_pre(spk - v1);
            b2 += sigm_pre(spk - v2);
            b3 += sigm_pre(spk - v3);
        }
        for (; k < m; ++k) b0 += sigm_pre(spk - s_simk[s_pl[off + k]]);
        float s = (b0 + b1) + (b2 + b3);
        // s includes q==p (=0.5): numerator = 0.5 + s
        part += (0.5f + s) * s_inv[p - h * HALF] * s_wsl[c];
    }

    for (int off = 32; off > 0; off >>= 1) part += __shfl_down(part, off, 64);
    if (lane == 0) s_red[wave] = part;
    __syncthreads();
    if (tid == 0) {
        float tot = 0.f;
#pragma unroll
        for (int w = 0; w < 6; ++w) tot += s_red[w];
        atomicAdd(out, -tot * (1.0f / (float)BB));
    }
}

extern "C" void kernel_launch(void* const* d_in, const int* in_sizes, int n_in,
                              void* d_out, int out_size, void* d_ws, size_t ws_size,
                              hipStream_t stream) {
    const float* preds = (const float*)d_in[0];       // (384,512) f32
    const float* softlabels = (const float*)d_in[1];  // (384,48) f32
    float* out = (float*)d_out;

    char* ws = (char*)d_ws;
    float* simk     = (float*)(ws + 0);         // 589824
    float* wclass   = (float*)(ws + 589824);    // 192
    int*   cls_off  = (int*)(ws + 590016);      // 256 (49 used)
    int*   cls_idx  = (int*)(ws + 590272);      // 73728
    int*   flat_pk  = (int*)(ws + 664000);      // 12288
    int*   ent_lo   = (int*)(ws + 676288);      // 12288
    int*   ent_hi   = (int*)(ws + 688576);      // 12288
    int*   nE3      = (int*)(ws + 700864);      // 12

    simprep_kernel<<<BB / 2 + 1, 384, 0, stream>>>(preds, softlabels, simk, wclass,
                                                   cls_idx, cls_off, flat_pk,
                                                   ent_lo, ent_hi, nE3, out);
    mega_kernel<<<BB * 2, 384, 0, stream>>>(simk, softlabels, wclass, cls_off,
                                            flat_pk, ent_lo, ent_hi, nE3, out);
}

// Round 9
// 59.350 us; speedup vs baseline: 1.5106x; 1.0021x over previous
//
#include <hip/hip_runtime.h>

// SoftSmoothAP on MI355X. B=384, C=48, D=512. Output: scalar f32 loss = 1 - AP.
//
//   simk[i,q] = <preds_i, preds_q> * 100*log2(e)        (pre-scaled)
//   sg(i,p,q) = 1/(1+exp2(simk[i,p] - simk[i,q]))       (clamp dropped: saturates
//               to 0/1 within 2e-22 of the reference's +-50 clip)
//   denom[i,p] = 0.5 + sum_{all q} sg                    (== 1 + sum_{q!=p} sg)
//   loss = 1 - (1/B) sum_{i,c} sl[i,c]*w[c] *
//            sum_{p in P_c} (0.5 + sum_{q in P_c} sg) / denom[i,p]
//
// R9 = R8 skeleton with the prep branch rebuilt: bitmask-transpose in LDS
// replaces stride-192B global column scans (prep was the hidden ~30us tail
// serializing on one CU before mega could start).

#define BB 384
#define CC 48
#define DD 512
#define HALF 192
#define MAXE 3072
#define SCALE 144.269504089f  // 100 * log2(e)

__device__ __forceinline__ float sigm_pre(float x) {
    return __builtin_amdgcn_rcpf(1.0f + __builtin_amdgcn_exp2f(x));
}

// ---- 1. sim rows (blocks 0..191, 2 rows each) + prep (block 192) -------------
__global__ __launch_bounds__(384) void simprep_kernel(
    const float* __restrict__ preds, const float* __restrict__ softlabels,
    float* __restrict__ simk, float* __restrict__ wclass,
    int* __restrict__ cls_idx, int* __restrict__ cls_off,
    int* __restrict__ flat_pack, int* __restrict__ ent_lo, int* __restrict__ ent_hi,
    int* __restrict__ nE3, float* __restrict__ out) {
    int tid = threadIdx.x;
    int wave = tid >> 6, lane = tid & 63;

    if (blockIdx.x < BB / 2) {
        // ---- sim: 2 rows per block, pre-scaled ----
        int i0 = blockIdx.x * 2;
        __shared__ __align__(16) float4 rows[2][DD / 4];
        const float4* src = reinterpret_cast<const float4*>(preds + i0 * DD);
        for (int v = tid; v < 2 * DD / 4; v += 384) (&rows[0][0])[v] = src[v];
        __syncthreads();
        int q = tid;
        const float4* pq = reinterpret_cast<const float4*>(preds + q * DD);
        float a0 = 0.f, a1 = 0.f;
#pragma unroll 8
        for (int d4 = 0; d4 < DD / 4; ++d4) {
            float4 b = pq[d4];
            float4 r0 = rows[0][d4];
            float4 r1 = rows[1][d4];
            a0 += r0.x * b.x + r0.y * b.y + r0.z * b.z + r0.w * b.w;
            a1 += r1.x * b.x + r1.y * b.y + r1.z * b.z + r1.w * b.w;
        }
        simk[i0 * BB + q] = a0 * SCALE;
        simk[(i0 + 1) * BB + q] = a1 * SCALE;
    } else {
        // ---- prep: bitmask transpose -> per-class lists via LDS-bit ballots
        __shared__ unsigned int s_mlo[BB];
        __shared__ unsigned int s_mhi[BB];
        __shared__ int s_cnt[CC];    // class count
        __shared__ int s_lcnt[CC];   // count with p < 192
        __shared__ int s_soff[CC + 1];
        __shared__ int s_loff[CC + 1];
        __shared__ int s_hoff[CC + 1];

        // thread p: contiguous row read, build 48-bit positivity mask
        {
            const float4* row = reinterpret_cast<const float4*>(softlabels + tid * CC);
            unsigned int lo = 0, hi = 0;
#pragma unroll
            for (int v = 0; v < 12; ++v) {
                float4 x = row[v];
                unsigned int b = (x.x > 0.f ? 1u : 0u) | (x.y > 0.f ? 2u : 0u) |
                                 (x.z > 0.f ? 4u : 0u) | (x.w > 0.f ? 8u : 0u);
                if (v < 8) lo |= b << (4 * v);
                else       hi |= b << (4 * (v - 8));
            }
            s_mlo[tid] = lo;
            s_mhi[tid] = hi;
        }
        __syncthreads();

        // each wave owns 8 classes; ballots test LDS mask bits (conflict-free)
        for (int j = 0; j < 8; ++j) {
            int c = wave * 8 + j;
            int base = 0, lbase = 0;
#pragma unroll
            for (int t = 0; t < BB / 64; ++t) {
                int p = t * 64 + lane;
                bool pos = ((c < 32 ? (s_mlo[p] >> c) : (s_mhi[p] >> (c - 32))) & 1u) != 0u;
                unsigned long long m = __ballot(pos);
                if (pos)
                    cls_idx[c * BB + base + __popcll(m & ((1ull << lane) - 1ull))] = p;
                base += __popcll(m);
                if (t < 3) lbase += __popcll(m);  // p<192 <=> t<3
            }
            if (lane == 0) {
                s_cnt[c] = base;
                s_lcnt[c] = lbase;
                wclass[c] = (base >= 4) ? (1.0f / (float)base) : 0.0f;
            }
        }
        __syncthreads();
        if (tid < 64) {
            int a = (tid < CC) ? s_cnt[tid] : 0;
            int l = (tid < CC) ? s_lcnt[tid] : 0;
            int hg = a - l;
#pragma unroll
            for (int d = 1; d < 64; d <<= 1) {
                int oa = __shfl_up(a, d, 64);
                int ol = __shfl_up(l, d, 64);
                int oh = __shfl_up(hg, d, 64);
                if (tid >= d) { a += oa; l += ol; hg += oh; }
            }
            if (tid < CC) { s_soff[tid + 1] = a; s_loff[tid + 1] = l; s_hoff[tid + 1] = hg; }
            if (tid == 0) { s_soff[0] = 0; s_loff[0] = 0; s_hoff[0] = 0; }
            if (tid == CC - 1) { nE3[0] = a; nE3[1] = l; nE3[2] = hg; }
        }
        __syncthreads();
        if (tid <= CC) cls_off[tid] = s_soff[tid];
        for (int c = wave; c < CC; c += 6) {
            int off = s_soff[c], cnt = s_cnt[c], L = s_lcnt[c];
            int lo = s_loff[c], ho = s_hoff[c];
            for (int k = lane; k < cnt; k += 64) {
                int p = cls_idx[c * BB + k];  // ascending p within class
                int pk = (c << 16) | p;
                flat_pack[off + k] = pk;
                if (k < L) ent_lo[lo + k] = pk;
                else       ent_hi[ho + (k - L)] = pk;
            }
        }
        if (tid == 0) out[0] = 1.0f;
    }
}

// ---- 2. mega768: denom (own p-half, 8 acc chains) + phaseB, block = (i, h) ---
__global__ __launch_bounds__(384) void mega_kernel(
    const float* __restrict__ simk, const float* __restrict__ softlabels,
    const float* __restrict__ wclass, const int* __restrict__ cls_off,
    const int* __restrict__ flat_pack, const int* __restrict__ ent_lo,
    const int* __restrict__ ent_hi, const int* __restrict__ nE3,
    float* __restrict__ out) {
    int i = blockIdx.x >> 1, h = blockIdx.x & 1;
    int tid = threadIdx.x;
    int wave = tid >> 6, lane = tid & 63;

    __shared__ __align__(16) float s_simk[BB];
    __shared__ float s_part[384];
    __shared__ float s_inv[HALF];
    __shared__ float s_wsl[CC];
    __shared__ int s_offs[CC + 1];
    __shared__ unsigned short s_pl[MAXE];
    __shared__ float s_red[6];

    int nE = nE3[0];
    s_simk[tid] = simk[i * BB + tid];
    if (tid < CC) s_wsl[tid] = wclass[tid] * softlabels[i * CC + tid];
    if (tid <= CC) s_offs[tid] = cls_off[tid];
    for (int e = tid; e < nE; e += 384) s_pl[e] = (unsigned short)(flat_pack[e] & 0xFFFF);
    __syncthreads();

    // --- denominators for this half: 2 threads/p over q-halves, 8 acc chains
    {
        int pl = tid % HALF;     // lane-contiguous p
        int chunk = tid / HALF;  // wave-uniform q-half
        float spk = s_simk[h * HALF + pl];
        const float4* sv = reinterpret_cast<const float4*>(s_simk + chunk * HALF);
        float a0 = 0.f, a1 = 0.f, a2 = 0.f, a3 = 0.f;
        float a4 = 0.f, a5 = 0.f, a6 = 0.f, a7 = 0.f;
#pragma unroll 4
        for (int t = 0; t < HALF / 8; ++t) {
            float4 v0 = sv[2 * t];      // same-address broadcast: conflict-free
            float4 v1 = sv[2 * t + 1];
            a0 += sigm_pre(spk - v0.x);
            a1 += sigm_pre(spk - v0.y);
            a2 += sigm_pre(spk - v0.z);
            a3 += sigm_pre(spk - v0.w);
            a4 += sigm_pre(spk - v1.x);
            a5 += sigm_pre(spk - v1.y);
            a6 += sigm_pre(spk - v1.z);
            a7 += sigm_pre(spk - v1.w);
        }
        s_part[tid] = ((a0 + a1) + (a2 + a3)) + ((a4 + a5) + (a6 + a7));
    }
    __syncthreads();
    if (tid < HALF) {
        float d = 0.5f + s_part[tid] + s_part[tid + HALF];
        s_inv[tid] = __builtin_amdgcn_rcpf(d);
    }
    __syncthreads();

    // --- positive-rank phase over this half's entries, 4-way unrolled gathers
    const int* ent = h ? ent_hi : ent_lo;
    int n = nE3[1 + h];
    float part = 0.f;
    for (int e = tid; e < n; e += 384) {
        int pk = ent[e];
        int c = pk >> 16, p = pk & 0xFFFF;
        int off = s_offs[c], m = s_offs[c + 1] - off;
        float spk = s_simk[p];
        float b0 = 0.f, b1 = 0.f, b2 = 0.f, b3 = 0.f;
        int k = 0;
        for (; k + 3 < m; k += 4) {
            float v0 = s_simk[s_pl[off + k]];
            float v1 = s_simk[s_pl[off + k + 1]];
            float v2 = s_simk[s_pl[off + k + 2]];
            float v3 = s_simk[s_pl[off + k + 3]];
            b0 += sigm_pre(spk - v0);
            b1 += sigm_pre(spk - v1);
            b2 += sigm_pre(spk - v2);
            b3 += sigm_pre(spk - v3);
        }
        for (; k < m; ++k) b0 += sigm_pre(spk - s_simk[s_pl[off + k]]);
        float s = (b0 + b1) + (b2 + b3);
        // s includes q==p (=0.5): numerator = 0.5 + s
        part += (0.5f + s) * s_inv[p - h * HALF] * s_wsl[c];
    }

    for (int off = 32; off > 0; off >>= 1) part += __shfl_down(part, off, 64);
    if (lane == 0) s_red[wave] = part;
    __syncthreads();
    if (tid == 0) {
        float tot = 0.f;
#pragma unroll
        for (int w = 0; w < 6; ++w) tot += s_red[w];
        atomicAdd(out, -tot * (1.0f / (float)BB));
    }
}

extern "C" void kernel_launch(void* const* d_in, const int* in_sizes, int n_in,
                              void* d_out, int out_size, void* d_ws, size_t ws_size,
                              hipStream_t stream) {
    const float* preds = (const float*)d_in[0];       // (384,512) f32
    const float* softlabels = (const float*)d_in[1];  // (384,48) f32
    float* out = (float*)d_out;

    char* ws = (char*)d_ws;
    float* simk     = (float*)(ws + 0);         // 589824
    float* wclass   = (float*)(ws + 589824);    // 192
    int*   cls_off  = (int*)(ws + 590016);      // 256 (49 used)
    int*   cls_idx  = (int*)(ws + 590272);      // 73728
    int*   flat_pk  = (int*)(ws + 664000);      // 12288
    int*   ent_lo   = (int*)(ws + 676288);      // 12288
    int*   ent_hi   = (int*)(ws + 688576);      // 12288
    int*   nE3      = (int*)(ws + 700864);      // 12

    simprep_kernel<<<BB / 2 + 1, 384, 0, stream>>>(preds, softlabels, simk, wclass,
                                                   cls_idx, cls_off, flat_pk,
                                                   ent_lo, ent_hi, nE3, out);
    mega_kernel<<<BB * 2, 384, 0, stream>>>(simk, softlabels, wclass, cls_off,
                                            flat_pk, ent_lo, ent_hi, nE3, out);
}